// Round 5
// baseline (367.233 us; speedup 1.0000x reference)
//
#include <hip/hip_runtime.h>
#include <cstddef>

#define HIDDEN 128
#define BN_EPS 1e-5f
#define SCAN_CHUNK 1024  // cnt elements per scan block
#define KC 32            // GEMM k-chunk

// RNE float->bf16 (manual, exact for non-NaN)
__device__ inline unsigned bf16_rne(float f) {
    unsigned u = __float_as_uint(f);
    return (u + 0x7fff + ((u >> 16) & 1)) >> 16;
}
__device__ inline unsigned pack2_bf16(float a, float b) {
    return bf16_rne(a) | (bf16_rne(b) << 16);
}

// unpack uint2 (4 bf16) -> float4
__device__ inline float4 unpack4(uint2 u) {
    return make_float4(__uint_as_float(u.x << 16),
                       __uint_as_float(u.x & 0xffff0000u),
                       __uint_as_float(u.y << 16),
                       __uint_as_float(u.y & 0xffff0000u));
}

// ---------- K1: zero degree counters + BN accumulators ----------
__global__ void k_zero(int* __restrict__ cnt, float* __restrict__ bn, int N) {
    int i = blockIdx.x * 256 + threadIdx.x;
    if (i < N) cnt[i] = 0;
    if (blockIdx.x == 0 && threadIdx.x < 256) bn[threadIdx.x] = 0.f;
}

// ---------- K2: in-degree histogram (4 edges/thread, fire-and-forget) ----------
__global__ void k_count(const int* __restrict__ col, int* __restrict__ cnt, int E) {
    int base = (blockIdx.x * 256 + threadIdx.x) * 4;
#pragma unroll
    for (int k = 0; k < 4; ++k) {
        int e = base + k;
        if (e < E) atomicAdd(&cnt[col[e]], 1);
    }
}

// ---------- K3a: per-block partial sums of cnt (1024 elems / block) ----------
__global__ __launch_bounds__(256) void k_partial(const int* __restrict__ cnt,
                                                 int* __restrict__ partials, int N) {
    __shared__ int s[256];
    int tid = threadIdx.x;
    int base = blockIdx.x * SCAN_CHUNK;
    int acc = 0;
#pragma unroll
    for (int k = 0; k < 4; ++k) {
        int idx = base + tid * 4 + k;
        if (idx < N) acc += cnt[idx];
    }
    s[tid] = acc;
    __syncthreads();
    for (int o = 128; o > 0; o >>= 1) {
        if (tid < o) s[tid] += s[tid + o];
        __syncthreads();
    }
    if (tid == 0) partials[blockIdx.x] = s[0];
}

// ---------- K3b: single-block exclusive scan of partials (all in LDS) ----------
__global__ __launch_bounds__(1024) void k_scan_partials(int* __restrict__ partials,
                                                        int* __restrict__ off,
                                                        int NB, int N) {
    __shared__ int s[1024];
    int tid = threadIdx.x;
    int v = (tid < NB) ? partials[tid] : 0;
    s[tid] = v;
    __syncthreads();
    for (int o = 1; o < 1024; o <<= 1) {
        int t = (tid >= o) ? s[tid - o] : 0;
        __syncthreads();
        s[tid] += t;
        __syncthreads();
    }
    if (tid < NB) partials[tid] = s[tid] - v;
    if (tid == NB - 1) off[N] = s[tid];
}

// ---------- K3c: block-local scan + base -> off, dinv, cnt reset ----------
__global__ __launch_bounds__(256) void k_finalize(int* __restrict__ cnt,
                                                  const int* __restrict__ partials,
                                                  int* __restrict__ off,
                                                  float* __restrict__ dinv, int N) {
    __shared__ int s[256];
    int tid = threadIdx.x;
    int base = blockIdx.x * SCAN_CHUNK;
    int c[4];
    int t = 0;
#pragma unroll
    for (int k = 0; k < 4; ++k) {
        int idx = base + tid * 4 + k;
        c[k] = (idx < N) ? cnt[idx] : 0;
        t += c[k];
    }
    s[tid] = t;
    __syncthreads();
    for (int o = 1; o < 256; o <<= 1) {
        int v = (tid >= o) ? s[tid - o] : 0;
        __syncthreads();
        s[tid] += v;
        __syncthreads();
    }
    int run = partials[blockIdx.x] + s[tid] - t;
#pragma unroll
    for (int k = 0; k < 4; ++k) {
        int idx = base + tid * 4 + k;
        if (idx < N) {
            off[idx] = run;
            run += c[k];
            dinv[idx] = rsqrtf((float)(c[k] + 1));  // deg includes self-loop
            cnt[idx] = 0;                           // reused as cursor in k_place
        }
    }
}

// ---------- K4: xu(bf16) = dinv .* (x @ W)  (fp32 math, K-chunked LDS) ----------
__global__ __launch_bounds__(256) void k_gemm(const float* __restrict__ x,
                                              const float* __restrict__ W,
                                              const float* __restrict__ dinv,
                                              unsigned* __restrict__ xu, int N) {
    __shared__ float4 ws4[KC * 32];   // 16 KB
    __shared__ float4 xt4[128 * 9];   // 18 KB (row stride 9: bank-quad spread)
    int tid = threadIdx.x;
    int row0 = blockIdx.x * 128;
    int rg = tid >> 4;  // 0..15 row group (8 rows)
    int cg = tid & 15;  // 0..15 col group (4+4 cols)

    float acc[8][8];
#pragma unroll
    for (int i = 0; i < 8; ++i)
#pragma unroll
        for (int j = 0; j < 8; ++j) acc[i][j] = 0.f;

    for (int q = 0; q < 4; ++q) {
        for (int t = tid; t < KC * 32; t += 256) {
            int k = t >> 5, c4 = t & 31;
            ws4[t] = ((const float4*)W)[(q * KC + k) * 32 + c4];
        }
        for (int t = tid; t < 128 * 8; t += 256) {
            int r = t >> 3, c4 = t & 7;
            int grow = row0 + r;
            float4 v = make_float4(0.f, 0.f, 0.f, 0.f);
            if (grow < N) v = ((const float4*)x)[grow * 32 + q * 8 + c4];
            xt4[r * 9 + c4] = v;
        }
        __syncthreads();

#pragma unroll
        for (int k4 = 0; k4 < 8; ++k4) {
            float4 xv[8];
#pragma unroll
            for (int i = 0; i < 8; ++i)
                xv[i] = xt4[(rg * 8 + i) * 9 + k4];
#pragma unroll
            for (int kk = 0; kk < 4; ++kk) {
                int k = k4 * 4 + kk;
                float4 w0 = ws4[k * 32 + cg];
                float4 w1 = ws4[k * 32 + 16 + cg];
#pragma unroll
                for (int i = 0; i < 8; ++i) {
                    float xs = ((const float*)&xv[i])[kk];
                    acc[i][0] = fmaf(xs, w0.x, acc[i][0]);
                    acc[i][1] = fmaf(xs, w0.y, acc[i][1]);
                    acc[i][2] = fmaf(xs, w0.z, acc[i][2]);
                    acc[i][3] = fmaf(xs, w0.w, acc[i][3]);
                    acc[i][4] = fmaf(xs, w1.x, acc[i][4]);
                    acc[i][5] = fmaf(xs, w1.y, acc[i][5]);
                    acc[i][6] = fmaf(xs, w1.z, acc[i][6]);
                    acc[i][7] = fmaf(xs, w1.w, acc[i][7]);
                }
            }
        }
        __syncthreads();
    }

#pragma unroll
    for (int i = 0; i < 8; ++i) {
        int grow = row0 + rg * 8 + i;
        if (grow < N) {
            float d = dinv[grow];
            uint2 p0, p1;
            p0.x = pack2_bf16(acc[i][0] * d, acc[i][1] * d);
            p0.y = pack2_bf16(acc[i][2] * d, acc[i][3] * d);
            p1.x = pack2_bf16(acc[i][4] * d, acc[i][5] * d);
            p1.y = pack2_bf16(acc[i][6] * d, acc[i][7] * d);
            ((uint2*)(xu + (size_t)grow * 64))[cg]      = p0;
            ((uint2*)(xu + (size_t)grow * 64))[16 + cg] = p1;
        }
    }
}

// ---------- K5: counting-sort edges by target (2 edges/thread) ----------
__global__ void k_place(const int* __restrict__ row, const int* __restrict__ col,
                        const int* __restrict__ off, int* __restrict__ cur,
                        int* __restrict__ srcs, int E) {
    int base = (blockIdx.x * 256 + threadIdx.x) * 2;
#pragma unroll
    for (int k = 0; k < 2; ++k) {
        int e = base + k;
        if (e < E) {
            int c = col[e];
            int p = atomicAdd(&cur[c], 1);
            srcs[off[c] + p] = row[e];
        }
    }
}

// ---------- K6: gather-aggregate, half-wave row pairs + fused BN stats ----------
// One wave-load (uint2/lane) fetches TWO 256B bf16 rows: lanes 0-31 row A,
// lanes 32-63 row B. Lane accumulates 4 cols; shfl_xor(32) merges halves.
__global__ __launch_bounds__(256) void k_gather(const unsigned* __restrict__ xu,
                                                const float* __restrict__ dinv,
                                                const int* __restrict__ off,
                                                const int* __restrict__ srcs,
                                                const float* __restrict__ b,
                                                float* __restrict__ out,
                                                float* __restrict__ bn, int N) {
    const uint2* xu2 = (const uint2*)xu;
    int tid = threadIdx.x;
    int lane = tid & 63;
    int half = lane >> 5;   // 0: even edges, 1: odd edges
    int hl = lane & 31;     // col group: cols 4hl..4hl+3
    unsigned hmask = half ? 0u : ~0u;  // mask for half-0-only contributions
    int w = (blockIdx.x * 256 + tid) >> 6;
    int nw = (gridDim.x * 256) >> 6;
    float4 bb = ((const float4*)b)[hl];

    float4 s = make_float4(0.f, 0.f, 0.f, 0.f);
    float4 qq = make_float4(0.f, 0.f, 0.f, 0.f);

    for (int i = w; i < N; i += nw) {
        float di = dinv[i];
        // self-loop row: broadcast 256B read, half-1 copy masked to 0
        uint2 su = xu2[(size_t)i * 32 + hl];
        su.x &= hmask;
        su.y &= hmask;
        float4 a = unpack4(su);
        int e0 = off[i], e1 = off[i + 1];
        int j = e0;
        // 2 pairs (4 rows) in flight
        for (; j + 4 <= e1; j += 4) {
            int ra = srcs[j + half];
            int rb = srcs[j + 2 + half];
            uint2 ua = xu2[(size_t)ra * 32 + hl];
            uint2 ub = xu2[(size_t)rb * 32 + hl];
            float4 fa = unpack4(ua);
            float4 fb = unpack4(ub);
            a.x += fa.x + fb.x;
            a.y += fa.y + fb.y;
            a.z += fa.z + fb.z;
            a.w += fa.w + fb.w;
        }
        for (; j + 2 <= e1; j += 2) {
            int r = srcs[j + half];
            uint2 u = xu2[(size_t)r * 32 + hl];
            float4 f = unpack4(u);
            a.x += f.x; a.y += f.y; a.z += f.z; a.w += f.w;
        }
        if (j < e1) {  // last odd edge: half 0 only
            int r = srcs[j];
            uint2 u = xu2[(size_t)r * 32 + hl];
            u.x &= hmask;
            u.y &= hmask;
            float4 f = unpack4(u);
            a.x += f.x; a.y += f.y; a.z += f.z; a.w += f.w;
        }
        // merge half partials (both halves end with identical totals)
        a.x += __shfl_xor(a.x, 32);
        a.y += __shfl_xor(a.y, 32);
        a.z += __shfl_xor(a.z, 32);
        a.w += __shfl_xor(a.w, 32);
        float4 o;
        o.x = fmaf(a.x, di, bb.x);
        o.y = fmaf(a.y, di, bb.y);
        o.z = fmaf(a.z, di, bb.z);
        o.w = fmaf(a.w, di, bb.w);
        if (half == 0)  // half-wave coalesced 512B store
            ((float4*)out)[(size_t)i * 32 + hl] = o;
        s.x += o.x; s.y += o.y; s.z += o.z; s.w += o.w;
        qq.x = fmaf(o.x, o.x, qq.x);
        qq.y = fmaf(o.y, o.y, qq.y);
        qq.z = fmaf(o.z, o.z, qq.z);
        qq.w = fmaf(o.w, o.w, qq.w);
    }

    // fused BN stats: halves hold identical s/q -> only half 0 contributes
    __shared__ float ssum[HIDDEN];
    __shared__ float ssq[HIDDEN];
    if (tid < HIDDEN) { ssum[tid] = 0.f; ssq[tid] = 0.f; }
    __syncthreads();
    if (half == 0) {
        atomicAdd(&ssum[4 * hl + 0], s.x);
        atomicAdd(&ssum[4 * hl + 1], s.y);
        atomicAdd(&ssum[4 * hl + 2], s.z);
        atomicAdd(&ssum[4 * hl + 3], s.w);
        atomicAdd(&ssq[4 * hl + 0], qq.x);
        atomicAdd(&ssq[4 * hl + 1], qq.y);
        atomicAdd(&ssq[4 * hl + 2], qq.z);
        atomicAdd(&ssq[4 * hl + 3], qq.w);
    }
    __syncthreads();
    if (tid < HIDDEN) {
        atomicAdd(&bn[tid],          ssum[tid]);
        atomicAdd(&bn[HIDDEN + tid], ssq[tid]);
    }
}

// ---------- K8: BN normalize (biased var) + gamma/beta + ReLU, in place ----------
__global__ __launch_bounds__(256) void k_apply(float* __restrict__ out,
                                               const float* __restrict__ bn,
                                               const float* __restrict__ gamma,
                                               const float* __restrict__ beta,
                                               int total4, float invN) {
    __shared__ float sc[HIDDEN], sh[HIDDEN];
    int tid = threadIdx.x;
    if (tid < HIDDEN) {
        float mean = bn[tid] * invN;
        float var = bn[HIDDEN + tid] * invN - mean * mean;
        float inv = rsqrtf(var + BN_EPS);
        float g = gamma[tid] * inv;
        sc[tid] = g;
        sh[tid] = beta[tid] - mean * g;
    }
    __syncthreads();
    int idx = blockIdx.x * 256 + tid;
    if (idx < total4) {
        float4 v = ((float4*)out)[idx];
        int c = (idx & 31) * 4;
        v.x = fmaxf(fmaf(v.x, sc[c],     sh[c]),     0.f);
        v.y = fmaxf(fmaf(v.y, sc[c + 1], sh[c + 1]), 0.f);
        v.z = fmaxf(fmaf(v.z, sc[c + 2], sh[c + 2]), 0.f);
        v.w = fmaxf(fmaf(v.w, sc[c + 3], sh[c + 3]), 0.f);
        ((float4*)out)[idx] = v;
    }
}

extern "C" void kernel_launch(void* const* d_in, const int* in_sizes, int n_in,
                              void* d_out, int out_size, void* d_ws, size_t ws_size,
                              hipStream_t stream) {
    const float* x     = (const float*)d_in[0];
    const int*   edges = (const int*)d_in[1];   // [2, E] int32 (JAX x64-off)
    const float* W     = (const float*)d_in[2];
    const float* b     = (const float*)d_in[3];
    const float* gamma = (const float*)d_in[4];
    const float* beta  = (const float*)d_in[5];
    float* out = (float*)d_out;

    int N = in_sizes[0] / HIDDEN;
    int E = in_sizes[1] / 2;
    const int* row = edges;      // sources
    const int* col = edges + E;  // targets

    int NB = (N + SCAN_CHUNK - 1) / SCAN_CHUNK;

    // workspace carve (~31 MB): xu(bf16) | dinv | cnt | off | srcs | bn | partials
    char* p = (char*)d_ws;
    unsigned* xu    = (unsigned*)p; p += (size_t)N * 64 * sizeof(unsigned);  // 128 bf16/row
    float* dinv     = (float*)p; p += (size_t)N * sizeof(float);
    int*   cnt      = (int*)p;   p += (size_t)N * sizeof(int);
    int*   off      = (int*)p;   p += ((size_t)N + 4) * sizeof(int);
    int*   srcs     = (int*)p;   p += (size_t)E * sizeof(int);
    float* bn       = (float*)p; p += 256 * sizeof(float);
    int*   partials = (int*)p;   p += (size_t)NB * sizeof(int);

    dim3 blk(256);
    k_zero <<<dim3((N + 255) / 256), blk, 0, stream>>>(cnt, bn, N);
    k_count<<<dim3((E + 1023) / 1024), blk, 0, stream>>>(col, cnt, E);
    k_partial<<<dim3(NB), blk, 0, stream>>>(cnt, partials, N);
    k_scan_partials<<<dim3(1), dim3(1024), 0, stream>>>(partials, off, NB, N);
    k_finalize<<<dim3(NB), blk, 0, stream>>>(cnt, partials, off, dinv, N);
    k_gemm <<<dim3((N + 127) / 128), blk, 0, stream>>>(x, W, dinv, xu, N);
    k_place<<<dim3((E + 511) / 512), blk, 0, stream>>>(row, col, off, cnt, srcs, E);
    k_gather<<<dim3(2048), blk, 0, stream>>>(xu, dinv, off, srcs, b, out, bn, N);
    int total4 = N * (HIDDEN / 4);
    k_apply<<<dim3((total4 + 255) / 256), blk, 0, stream>>>(out, bn, gamma, beta, total4,
                                                            1.0f / (float)N);
}

// Round 6
// 335.201 us; speedup vs baseline: 1.0956x; 1.0956x over previous
//
#include <hip/hip_runtime.h>
#include <cstddef>

#define HIDDEN 128
#define BN_EPS 1e-5f
#define SCAN_CHUNK 1024  // cnt elements per scan block
#define KS 136           // LDS row stride (ushort): 272B = 17*16B -> aligned b128, bank-spread

typedef __attribute__((ext_vector_type(8))) short short8;   // 8 bf16 (4 VGPRs)
typedef __attribute__((ext_vector_type(4))) float float4v;  // MFMA acc

// RNE float->bf16 (manual, exact for non-NaN)
__device__ inline unsigned bf16_rne(float f) {
    unsigned u = __float_as_uint(f);
    return (u + 0x7fff + ((u >> 16) & 1)) >> 16;
}
__device__ inline unsigned pack2_bf16(float a, float b) {
    return bf16_rne(a) | (bf16_rne(b) << 16);
}

// ---------- K2: in-degree histogram (4 edges/thread) ----------
__global__ void k_count(const int* __restrict__ col, int* __restrict__ cnt, int E) {
    int base = (blockIdx.x * 256 + threadIdx.x) * 4;
#pragma unroll
    for (int k = 0; k < 4; ++k) {
        int e = base + k;
        if (e < E) atomicAdd(&cnt[col[e]], 1);
    }
}

// ---------- K3a: per-block partial sums of cnt ----------
__global__ __launch_bounds__(256) void k_partial(const int* __restrict__ cnt,
                                                 int* __restrict__ partials, int N) {
    __shared__ int s[256];
    int tid = threadIdx.x;
    int base = blockIdx.x * SCAN_CHUNK;
    int acc = 0;
#pragma unroll
    for (int k = 0; k < 4; ++k) {
        int idx = base + tid * 4 + k;
        if (idx < N) acc += cnt[idx];
    }
    s[tid] = acc;
    __syncthreads();
    for (int o = 128; o > 0; o >>= 1) {
        if (tid < o) s[tid] += s[tid + o];
        __syncthreads();
    }
    if (tid == 0) partials[blockIdx.x] = s[0];
}

// ---------- K3b: single-block exclusive scan of partials ----------
__global__ __launch_bounds__(1024) void k_scan_partials(int* __restrict__ partials,
                                                        int* __restrict__ off,
                                                        int NB, int N) {
    __shared__ int s[1024];
    int tid = threadIdx.x;
    int v = (tid < NB) ? partials[tid] : 0;
    s[tid] = v;
    __syncthreads();
    for (int o = 1; o < 1024; o <<= 1) {
        int t = (tid >= o) ? s[tid - o] : 0;
        __syncthreads();
        s[tid] += t;
        __syncthreads();
    }
    if (tid < NB) partials[tid] = s[tid] - v;
    if (tid == NB - 1) off[N] = s[tid];
}

// ---------- K3c: block-local scan + base -> off, dinv, cnt reset ----------
__global__ __launch_bounds__(256) void k_finalize(int* __restrict__ cnt,
                                                  const int* __restrict__ partials,
                                                  int* __restrict__ off,
                                                  float* __restrict__ dinv, int N) {
    __shared__ int s[256];
    int tid = threadIdx.x;
    int base = blockIdx.x * SCAN_CHUNK;
    int c[4];
    int t = 0;
#pragma unroll
    for (int k = 0; k < 4; ++k) {
        int idx = base + tid * 4 + k;
        c[k] = (idx < N) ? cnt[idx] : 0;
        t += c[k];
    }
    s[tid] = t;
    __syncthreads();
    for (int o = 1; o < 256; o <<= 1) {
        int v = (tid >= o) ? s[tid - o] : 0;
        __syncthreads();
        s[tid] += v;
        __syncthreads();
    }
    int run = partials[blockIdx.x] + s[tid] - t;
#pragma unroll
    for (int k = 0; k < 4; ++k) {
        int idx = base + tid * 4 + k;
        if (idx < N) {
            off[idx] = run;
            run += c[k];
            dinv[idx] = rsqrtf((float)(c[k] + 1));  // deg includes self-loop
            cnt[idx] = 0;                           // reused as cursor in k_place
        }
    }
}

// ---------- K4: xu(bf16) = dinv .* (x @ W) via bf16 MFMA ----------
// 128x128 tile/block, K=128 staged once as bf16 in LDS (A 34KB + B^T 34KB -> 2 blk/CU).
// 4 waves: wave w owns rows [32w,32w+32); 2x8 tiles of 16x16x32 MFMA, 64 MFMA/wave.
// Fragment maps (m89-verified C; standard A/B): A[m][k]: m=lane&15, k=8*(lane>>4)+j;
// B[k][n]: n=lane&15, k=8*(lane>>4)+j; C: col=lane&15, row=4*(lane>>4)+reg.
__global__ __launch_bounds__(256) void k_gemm(const float* __restrict__ x,
                                              const float* __restrict__ W,
                                              const float* __restrict__ dinv,
                                              unsigned short* __restrict__ xus, int N) {
    __shared__ unsigned short lA[128 * KS];  // [m][k] bf16
    __shared__ unsigned short lB[128 * KS];  // [n][k] bf16 (W transposed)
    int tid = threadIdx.x;
    int row0 = blockIdx.x * 128;
    int wv = tid >> 6;
    int lane = tid & 63;
    int l15 = lane & 15;
    int lq = lane >> 4;  // 0..3

    // stage x tile: float4 reads, bf16 ds_write_b64
    for (int it = 0; it < 16; ++it) {
        int idx4 = it * 256 + tid;          // 4096 float4s
        int m = idx4 >> 5, c4 = idx4 & 31;  // 32 float4 per row
        int grow = row0 + m;
        float4 v = make_float4(0.f, 0.f, 0.f, 0.f);
        if (grow < N) v = ((const float4*)x)[(size_t)grow * 32 + c4];
        uint2 pk;
        pk.x = pack2_bf16(v.x, v.y);
        pk.y = pack2_bf16(v.z, v.w);
        *(uint2*)&lA[m * KS + c4 * 4] = pk;
    }
    // stage W transposed: coalesced f32 reads along n, scattered u16 LDS writes
    for (int it = 0; it < 64; ++it) {
        int idx = it * 256 + tid;          // 16384 elems
        int k = idx >> 7, n = idx & 127;
        lB[n * KS + k] = (unsigned short)bf16_rne(W[(size_t)k * 128 + n]);
    }
    __syncthreads();

    float4v acc[2][8];
#pragma unroll
    for (int i = 0; i < 2; ++i)
#pragma unroll
        for (int j = 0; j < 8; ++j) acc[i][j] = (float4v){0.f, 0.f, 0.f, 0.f};

#pragma unroll
    for (int kc = 0; kc < 4; ++kc) {
        int ko = kc * 32 + lq * 8;
        short8 a0 = *(const short8*)&lA[(wv * 32 + l15) * KS + ko];
        short8 a1 = *(const short8*)&lA[(wv * 32 + 16 + l15) * KS + ko];
        short8 bfr[8];
#pragma unroll
        for (int nt = 0; nt < 8; ++nt)
            bfr[nt] = *(const short8*)&lB[(nt * 16 + l15) * KS + ko];
#pragma unroll
        for (int nt = 0; nt < 8; ++nt) {
            acc[0][nt] = __builtin_amdgcn_mfma_f32_16x16x32_bf16(a0, bfr[nt], acc[0][nt], 0, 0, 0);
            acc[1][nt] = __builtin_amdgcn_mfma_f32_16x16x32_bf16(a1, bfr[nt], acc[1][nt], 0, 0, 0);
        }
    }

    // epilogue: r = row0 + 32w + 16mt + 4lq + reg, col = 16nt + l15
#pragma unroll
    for (int mt = 0; mt < 2; ++mt) {
#pragma unroll
        for (int reg = 0; reg < 4; ++reg) {
            int r = row0 + wv * 32 + mt * 16 + lq * 4 + reg;
            if (r < N) {
                float d = dinv[r];
#pragma unroll
                for (int nt = 0; nt < 8; ++nt) {
                    float vv = acc[mt][nt][reg] * d;
                    xus[(size_t)r * 128 + nt * 16 + l15] = (unsigned short)bf16_rne(vv);
                }
            }
        }
    }
}

// ---------- K5: counting-sort edges by target (2 edges/thread) ----------
__global__ void k_place(const int* __restrict__ row, const int* __restrict__ col,
                        const int* __restrict__ off, int* __restrict__ cur,
                        int* __restrict__ srcs, int E) {
    int base = (blockIdx.x * 256 + threadIdx.x) * 2;
#pragma unroll
    for (int k = 0; k < 2; ++k) {
        int e = base + k;
        if (e < E) {
            int c = col[e];
            int p = atomicAdd(&cur[c], 1);
            srcs[off[c] + p] = row[e];
        }
    }
}

// ---------- K6: gather-aggregate (bf16 rows, unroll x4) + fused BN stats ----------
// agg[i] = dinv_i * (sum_{r->i} xu[r] + xu[i]) + b   (xu pre-scaled by dinv)
__global__ __launch_bounds__(256) void k_gather(const unsigned* __restrict__ xu,
                                                const float* __restrict__ dinv,
                                                const int* __restrict__ off,
                                                const int* __restrict__ srcs,
                                                const float* __restrict__ b,
                                                float* __restrict__ out,
                                                float* __restrict__ bn, int N) {
    int tid = threadIdx.x;
    int lane = tid & 63;
    int w = (blockIdx.x * 256 + tid) >> 6;
    int nw = (gridDim.x * 256) >> 6;
    float2 bb = ((const float2*)b)[lane];
    float2 s = make_float2(0.f, 0.f), qq = make_float2(0.f, 0.f);
    for (int i = w; i < N; i += nw) {
        float di = dinv[i];
        unsigned su = xu[(size_t)i * 64 + lane];  // self-loop (pre-scaled)
        float ax = __uint_as_float(su << 16);
        float ay = __uint_as_float(su & 0xffff0000u);
        int e0 = off[i], e1 = off[i + 1];
        int j = e0;
        for (; j + 4 <= e1; j += 4) {  // 4 rows in flight
            int r0 = srcs[j], r1 = srcs[j + 1], r2 = srcs[j + 2], r3 = srcs[j + 3];
            unsigned u0 = xu[(size_t)r0 * 64 + lane];
            unsigned u1 = xu[(size_t)r1 * 64 + lane];
            unsigned u2 = xu[(size_t)r2 * 64 + lane];
            unsigned u3 = xu[(size_t)r3 * 64 + lane];
            ax += __uint_as_float(u0 << 16) + __uint_as_float(u1 << 16)
                + __uint_as_float(u2 << 16) + __uint_as_float(u3 << 16);
            ay += __uint_as_float(u0 & 0xffff0000u) + __uint_as_float(u1 & 0xffff0000u)
                + __uint_as_float(u2 & 0xffff0000u) + __uint_as_float(u3 & 0xffff0000u);
        }
        for (; j < e1; ++j) {
            int r = srcs[j];
            unsigned u = xu[(size_t)r * 64 + lane];
            ax += __uint_as_float(u << 16);
            ay += __uint_as_float(u & 0xffff0000u);
        }
        float ox = fmaf(ax, di, bb.x);
        float oy = fmaf(ay, di, bb.y);
        ((float2*)out)[(size_t)i * 64 + lane] = make_float2(ox, oy);
        s.x += ox;
        s.y += oy;
        qq.x = fmaf(ox, ox, qq.x);
        qq.y = fmaf(oy, oy, qq.y);
    }
    // fused BN stats: block-level LDS reduce, one atomic set per block
    __shared__ float ssum[HIDDEN];
    __shared__ float ssq[HIDDEN];
    if (tid < HIDDEN) { ssum[tid] = 0.f; ssq[tid] = 0.f; }
    __syncthreads();
    atomicAdd(&ssum[2 * lane],     s.x);
    atomicAdd(&ssum[2 * lane + 1], s.y);
    atomicAdd(&ssq[2 * lane],      qq.x);
    atomicAdd(&ssq[2 * lane + 1],  qq.y);
    __syncthreads();
    if (tid < HIDDEN) {
        atomicAdd(&bn[tid],          ssum[tid]);
        atomicAdd(&bn[HIDDEN + tid], ssq[tid]);
    }
}

// ---------- K8: BN normalize (biased var) + gamma/beta + ReLU, in place ----------
__global__ __launch_bounds__(256) void k_apply(float* __restrict__ out,
                                               const float* __restrict__ bn,
                                               const float* __restrict__ gamma,
                                               const float* __restrict__ beta,
                                               int total4, float invN) {
    __shared__ float sc[HIDDEN], sh[HIDDEN];
    int tid = threadIdx.x;
    if (tid < HIDDEN) {
        float mean = bn[tid] * invN;
        float var = bn[HIDDEN + tid] * invN - mean * mean;
        float inv = rsqrtf(var + BN_EPS);
        float g = gamma[tid] * inv;
        sc[tid] = g;
        sh[tid] = beta[tid] - mean * g;
    }
    __syncthreads();
    int idx = blockIdx.x * 256 + tid;
    if (idx < total4) {
        float4 v = ((float4*)out)[idx];
        int c = (idx & 31) * 4;
        v.x = fmaxf(fmaf(v.x, sc[c],     sh[c]),     0.f);
        v.y = fmaxf(fmaf(v.y, sc[c + 1], sh[c + 1]), 0.f);
        v.z = fmaxf(fmaf(v.z, sc[c + 2], sh[c + 2]), 0.f);
        v.w = fmaxf(fmaf(v.w, sc[c + 3], sh[c + 3]), 0.f);
        ((float4*)out)[idx] = v;
    }
}

extern "C" void kernel_launch(void* const* d_in, const int* in_sizes, int n_in,
                              void* d_out, int out_size, void* d_ws, size_t ws_size,
                              hipStream_t stream) {
    const float* x     = (const float*)d_in[0];
    const int*   edges = (const int*)d_in[1];   // [2, E] int32 (JAX x64-off)
    const float* W     = (const float*)d_in[2];
    const float* b     = (const float*)d_in[3];
    const float* gamma = (const float*)d_in[4];
    const float* beta  = (const float*)d_in[5];
    float* out = (float*)d_out;

    int N = in_sizes[0] / HIDDEN;
    int E = in_sizes[1] / 2;
    const int* row = edges;      // sources
    const int* col = edges + E;  // targets

    int NB = (N + SCAN_CHUNK - 1) / SCAN_CHUNK;

    // workspace carve (~31 MB): xu(bf16) | dinv | cnt | off | srcs | bn | partials
    char* p = (char*)d_ws;
    unsigned* xu    = (unsigned*)p; p += (size_t)N * 64 * sizeof(unsigned);  // 128 bf16/row
    float* dinv     = (float*)p; p += (size_t)N * sizeof(float);
    int*   cnt      = (int*)p;   p += (size_t)N * sizeof(int);
    int*   off      = (int*)p;   p += ((size_t)N + 4) * sizeof(int);
    int*   srcs     = (int*)p;   p += (size_t)E * sizeof(int);
    float* bn       = (float*)p; p += 256 * sizeof(float);
    int*   partials = (int*)p;   p += (size_t)NB * sizeof(int);

    dim3 blk(256);
    hipMemsetAsync(cnt, 0, (size_t)N * sizeof(int), stream);
    hipMemsetAsync(bn, 0, 256 * sizeof(float), stream);
    k_count<<<dim3((E + 1023) / 1024), blk, 0, stream>>>(col, cnt, E);
    k_partial<<<dim3(NB), blk, 0, stream>>>(cnt, partials, N);
    k_scan_partials<<<dim3(1), dim3(1024), 0, stream>>>(partials, off, NB, N);
    k_finalize<<<dim3(NB), blk, 0, stream>>>(cnt, partials, off, dinv, N);
    k_gemm<<<dim3((N + 127) / 128), blk, 0, stream>>>(x, W, dinv, (unsigned short*)xu, N);
    k_place<<<dim3((E + 511) / 512), blk, 0, stream>>>(row, col, off, cnt, srcs, E);
    k_gather<<<dim3(2048), blk, 0, stream>>>(xu, dinv, off, srcs, b, out, bn, N);
    int total4 = N * (HIDDEN / 4);
    k_apply<<<dim3((total4 + 255) / 256), blk, 0, stream>>>(out, bn, gamma, beta, total4,
                                                            1.0f / (float)N);
}

// Round 7
// 335.036 us; speedup vs baseline: 1.0961x; 1.0005x over previous
//
#include <hip/hip_runtime.h>
#include <cstddef>

#define HIDDEN 128
#define BN_EPS 1e-5f
#define SCAN_CHUNK 1024  // cnt elements per scan block
#define KS 136           // GEMM LDS row stride (ushort): 272B -> aligned b128, bank-spread

typedef __attribute__((ext_vector_type(8))) short short8;   // 8 bf16 (4 VGPRs)
typedef __attribute__((ext_vector_type(4))) float float4v;  // MFMA acc

// RNE float->bf16 (manual, exact for non-NaN)
__device__ inline unsigned bf16_rne(float f) {
    unsigned u = __float_as_uint(f);
    return (u + 0x7fff + ((u >> 16) & 1)) >> 16;
}
__device__ inline unsigned pack2_bf16(float a, float b) {
    return bf16_rne(a) | (bf16_rne(b) << 16);
}

// ---------- K1: in-degree histogram (int4-vectorized col reads) ----------
__global__ void k_count(const int* __restrict__ col, int* __restrict__ cnt, int E) {
    int base = (blockIdx.x * 256 + threadIdx.x) * 4;
    if (base + 3 < E) {
        int4 c = *(const int4*)&col[base];
        atomicAdd(&cnt[c.x], 1);
        atomicAdd(&cnt[c.y], 1);
        atomicAdd(&cnt[c.z], 1);
        atomicAdd(&cnt[c.w], 1);
    } else {
        for (int k = 0; k < 4; ++k) {
            int e = base + k;
            if (e < E) atomicAdd(&cnt[col[e]], 1);
        }
    }
}

// ---------- K2: fused CSR-build scan (decoupled lookback, 1 dispatch) ----------
// flags[b]: (status<<32)|value. status 1=aggregate, 2=inclusive. All NB<=256
// blocks are co-resident, aggregates publish unconditionally -> no deadlock.
__global__ __launch_bounds__(256) void k_csr(int* __restrict__ cnt,
                                             unsigned long long* __restrict__ flags,
                                             int* __restrict__ off,
                                             float* __restrict__ dinv, int N, int NB) {
    __shared__ int s[256];
    __shared__ int sbase;
    int tid = threadIdx.x;
    int b = blockIdx.x;
    int base = b * SCAN_CHUNK;
    int c[4];
    int t = 0;
#pragma unroll
    for (int k = 0; k < 4; ++k) {
        int idx = base + tid * 4 + k;
        c[k] = (idx < N) ? cnt[idx] : 0;
        t += c[k];
    }
    s[tid] = t;
    __syncthreads();
    for (int o = 1; o < 256; o <<= 1) {  // Hillis-Steele inclusive over thread totals
        int v = (tid >= o) ? s[tid - o] : 0;
        __syncthreads();
        s[tid] += v;
        __syncthreads();
    }
    int incl = s[tid];
    int total = s[255];

    if (b == 0) {
        if (tid == 0) {
            sbase = 0;
            atomicExch(&flags[0], (2ULL << 32) | (unsigned)total);
        }
    } else {
        if (tid == 0) atomicExch(&flags[b], (1ULL << 32) | (unsigned)total);
        if (tid < 64) {  // wave-0 parallel lookback, 64 predecessors per round
            int excl = 0;
            int look = b - 1;
            while (true) {
                int idx = look - tid;
                unsigned long long v = 0;
                if (idx >= 0) {
                    do { v = atomicAdd(&flags[idx], 0ULL); } while ((v >> 32) == 0ULL);
                }
                int st = (int)(v >> 32);
                unsigned long long ball = __ballot(idx >= 0 && st == 2);
                int firstInc = ball ? (__ffsll(ball) - 1) : 64;
                int val = (idx >= 0 && tid <= firstInc) ? (int)(v & 0xffffffffULL) : 0;
#pragma unroll
                for (int o = 32; o > 0; o >>= 1) val += __shfl_down(val, o);
                if (tid == 0) excl += val;
                if (firstInc < 64 || look - 64 < 0) break;
                look -= 64;
            }
            if (tid == 0) {
                sbase = excl;
                atomicExch(&flags[b], (2ULL << 32) | (unsigned)(excl + total));
            }
        }
    }
    __syncthreads();

    int run = sbase + incl - t;  // exclusive prefix for this thread
#pragma unroll
    for (int k = 0; k < 4; ++k) {
        int idx = base + tid * 4 + k;
        if (idx < N) {
            off[idx] = run;
            run += c[k];
            dinv[idx] = rsqrtf((float)(c[k] + 1));  // deg includes self-loop
            cnt[idx] = 0;                           // reused as cursor in k_place
        }
    }
    if (b == NB - 1 && tid == 255) off[N] = sbase + incl;
}

// ---------- K3: xu(bf16) = dinv .* (x @ W) via bf16 MFMA ----------
// 128x128 tile/block, K=128 staged once as bf16 in LDS (A 34KB + B^T 34KB -> 2 blk/CU).
// 4 waves; 2x8 tiles of 16x16x32 MFMA, 64 MFMA/wave. Layouts verified by R6 absmax.
__global__ __launch_bounds__(256) void k_gemm(const float* __restrict__ x,
                                              const float* __restrict__ W,
                                              const float* __restrict__ dinv,
                                              unsigned short* __restrict__ xus, int N) {
    __shared__ unsigned short lA[128 * KS];  // [m][k] bf16
    __shared__ unsigned short lB[128 * KS];  // [n][k] bf16 (W transposed)
    int tid = threadIdx.x;
    int row0 = blockIdx.x * 128;
    int wv = tid >> 6;
    int lane = tid & 63;
    int l15 = lane & 15;
    int lq = lane >> 4;  // 0..3

    for (int it = 0; it < 16; ++it) {
        int idx4 = it * 256 + tid;
        int m = idx4 >> 5, c4 = idx4 & 31;
        int grow = row0 + m;
        float4 v = make_float4(0.f, 0.f, 0.f, 0.f);
        if (grow < N) v = ((const float4*)x)[(size_t)grow * 32 + c4];
        uint2 pk;
        pk.x = pack2_bf16(v.x, v.y);
        pk.y = pack2_bf16(v.z, v.w);
        *(uint2*)&lA[m * KS + c4 * 4] = pk;
    }
    for (int it = 0; it < 64; ++it) {
        int idx = it * 256 + tid;
        int k = idx >> 7, n = idx & 127;
        lB[n * KS + k] = (unsigned short)bf16_rne(W[(size_t)k * 128 + n]);
    }
    __syncthreads();

    float4v acc[2][8];
#pragma unroll
    for (int i = 0; i < 2; ++i)
#pragma unroll
        for (int j = 0; j < 8; ++j) acc[i][j] = (float4v){0.f, 0.f, 0.f, 0.f};

#pragma unroll
    for (int kc = 0; kc < 4; ++kc) {
        int ko = kc * 32 + lq * 8;
        short8 a0 = *(const short8*)&lA[(wv * 32 + l15) * KS + ko];
        short8 a1 = *(const short8*)&lA[(wv * 32 + 16 + l15) * KS + ko];
        short8 bfr[8];
#pragma unroll
        for (int nt = 0; nt < 8; ++nt)
            bfr[nt] = *(const short8*)&lB[(nt * 16 + l15) * KS + ko];
#pragma unroll
        for (int nt = 0; nt < 8; ++nt) {
            acc[0][nt] = __builtin_amdgcn_mfma_f32_16x16x32_bf16(a0, bfr[nt], acc[0][nt], 0, 0, 0);
            acc[1][nt] = __builtin_amdgcn_mfma_f32_16x16x32_bf16(a1, bfr[nt], acc[1][nt], 0, 0, 0);
        }
    }

#pragma unroll
    for (int mt = 0; mt < 2; ++mt) {
#pragma unroll
        for (int reg = 0; reg < 4; ++reg) {
            int r = row0 + wv * 32 + mt * 16 + lq * 4 + reg;
            if (r < N) {
                float d = dinv[r];
#pragma unroll
                for (int nt = 0; nt < 8; ++nt) {
                    float vv = acc[mt][nt][reg] * d;
                    xus[(size_t)r * 128 + nt * 16 + l15] = (unsigned short)bf16_rne(vv);
                }
            }
        }
    }
}

// ---------- K4: counting-sort edges by target (2 edges/thread) ----------
__global__ void k_place(const int* __restrict__ row, const int* __restrict__ col,
                        const int* __restrict__ off, int* __restrict__ cur,
                        int* __restrict__ srcs, int E) {
    int base = (blockIdx.x * 256 + threadIdx.x) * 2;
#pragma unroll
    for (int k = 0; k < 2; ++k) {
        int e = base + k;
        if (e < E) {
            int c = col[e];
            int p = atomicAdd(&cur[c], 1);
            srcs[off[c] + p] = row[e];
        }
    }
}

// ---------- K5: gather-aggregate (bf16 rows, 8 rows in flight) + BN stats ----------
// agg[i] = dinv_i * (sum_{r->i} xu[r] + xu[i]) + b   (xu pre-scaled by dinv)
__global__ __launch_bounds__(256) void k_gather(const unsigned* __restrict__ xu,
                                                const float* __restrict__ dinv,
                                                const int* __restrict__ off,
                                                const int* __restrict__ srcs,
                                                const float* __restrict__ b,
                                                float* __restrict__ out,
                                                float* __restrict__ bn, int N) {
    int tid = threadIdx.x;
    int lane = tid & 63;
    int w = (blockIdx.x * 256 + tid) >> 6;
    int nw = (gridDim.x * 256) >> 6;
    float2 bb = ((const float2*)b)[lane];
    float2 s = make_float2(0.f, 0.f), qq = make_float2(0.f, 0.f);
    for (int i = w; i < N; i += nw) {
        float di = dinv[i];
        unsigned su = xu[(size_t)i * 64 + lane];  // self-loop (pre-scaled)
        float ax = __uint_as_float(su << 16);
        float ay = __uint_as_float(su & 0xffff0000u);
        int e0 = off[i], e1 = off[i + 1];
        int j = e0;
        for (; j + 8 <= e1; j += 8) {  // 8 rows in flight
            int r[8];
#pragma unroll
            for (int k = 0; k < 8; ++k) r[k] = srcs[j + k];
            unsigned u[8];
#pragma unroll
            for (int k = 0; k < 8; ++k) u[k] = xu[(size_t)r[k] * 64 + lane];
#pragma unroll
            for (int k = 0; k < 8; ++k) {
                ax += __uint_as_float(u[k] << 16);
                ay += __uint_as_float(u[k] & 0xffff0000u);
            }
        }
        for (; j + 4 <= e1; j += 4) {  // 4 rows in flight
            int r0 = srcs[j], r1 = srcs[j + 1], r2 = srcs[j + 2], r3 = srcs[j + 3];
            unsigned u0 = xu[(size_t)r0 * 64 + lane];
            unsigned u1 = xu[(size_t)r1 * 64 + lane];
            unsigned u2 = xu[(size_t)r2 * 64 + lane];
            unsigned u3 = xu[(size_t)r3 * 64 + lane];
            ax += __uint_as_float(u0 << 16) + __uint_as_float(u1 << 16)
                + __uint_as_float(u2 << 16) + __uint_as_float(u3 << 16);
            ay += __uint_as_float(u0 & 0xffff0000u) + __uint_as_float(u1 & 0xffff0000u)
                + __uint_as_float(u2 & 0xffff0000u) + __uint_as_float(u3 & 0xffff0000u);
        }
        for (; j < e1; ++j) {
            int r = srcs[j];
            unsigned u = xu[(size_t)r * 64 + lane];
            ax += __uint_as_float(u << 16);
            ay += __uint_as_float(u & 0xffff0000u);
        }
        float ox = fmaf(ax, di, bb.x);
        float oy = fmaf(ay, di, bb.y);
        ((float2*)out)[(size_t)i * 64 + lane] = make_float2(ox, oy);
        s.x += ox;
        s.y += oy;
        qq.x = fmaf(ox, ox, qq.x);
        qq.y = fmaf(oy, oy, qq.y);
    }
    // fused BN stats: block-level LDS reduce, one atomic set per block
    __shared__ float ssum[HIDDEN];
    __shared__ float ssq[HIDDEN];
    if (tid < HIDDEN) { ssum[tid] = 0.f; ssq[tid] = 0.f; }
    __syncthreads();
    atomicAdd(&ssum[2 * lane],     s.x);
    atomicAdd(&ssum[2 * lane + 1], s.y);
    atomicAdd(&ssq[2 * lane],      qq.x);
    atomicAdd(&ssq[2 * lane + 1],  qq.y);
    __syncthreads();
    if (tid < HIDDEN) {
        atomicAdd(&bn[tid],          ssum[tid]);
        atomicAdd(&bn[HIDDEN + tid], ssq[tid]);
    }
}

// ---------- K6: BN normalize (biased var) + gamma/beta + ReLU, in place ----------
__global__ __launch_bounds__(256) void k_apply(float* __restrict__ out,
                                               const float* __restrict__ bn,
                                               const float* __restrict__ gamma,
                                               const float* __restrict__ beta,
                                               int total4, float invN) {
    __shared__ float sc[HIDDEN], sh[HIDDEN];
    int tid = threadIdx.x;
    if (tid < HIDDEN) {
        float mean = bn[tid] * invN;
        float var = bn[HIDDEN + tid] * invN - mean * mean;
        float inv = rsqrtf(var + BN_EPS);
        float g = gamma[tid] * inv;
        sc[tid] = g;
        sh[tid] = beta[tid] - mean * g;
    }
    __syncthreads();
    int idx = blockIdx.x * 256 + tid;
    if (idx < total4) {
        float4 v = ((float4*)out)[idx];
        int c = (idx & 31) * 4;
        v.x = fmaxf(fmaf(v.x, sc[c],     sh[c]),     0.f);
        v.y = fmaxf(fmaf(v.y, sc[c + 1], sh[c + 1]), 0.f);
        v.z = fmaxf(fmaf(v.z, sc[c + 2], sh[c + 2]), 0.f);
        v.w = fmaxf(fmaf(v.w, sc[c + 3], sh[c + 3]), 0.f);
        ((float4*)out)[idx] = v;
    }
}

extern "C" void kernel_launch(void* const* d_in, const int* in_sizes, int n_in,
                              void* d_out, int out_size, void* d_ws, size_t ws_size,
                              hipStream_t stream) {
    const float* x     = (const float*)d_in[0];
    const int*   edges = (const int*)d_in[1];   // [2, E] int32 (JAX x64-off)
    const float* W     = (const float*)d_in[2];
    const float* b     = (const float*)d_in[3];
    const float* gamma = (const float*)d_in[4];
    const float* beta  = (const float*)d_in[5];
    float* out = (float*)d_out;

    int N = in_sizes[0] / HIDDEN;
    int E = in_sizes[1] / 2;
    const int* row = edges;      // sources
    const int* col = edges + E;  // targets

    int NB = (N + SCAN_CHUNK - 1) / SCAN_CHUNK;

    // workspace carve (~31 MB). Zeroed region is contiguous: cnt | flags | bn.
    char* p = (char*)d_ws;
    unsigned* xu = (unsigned*)p; p += (size_t)N * 64 * sizeof(unsigned);  // 128 bf16/row
    float* dinv  = (float*)p; p += (size_t)N * sizeof(float);
    int*   cnt   = (int*)p;   p += (size_t)N * sizeof(int);               // zeroed
    unsigned long long* flags = (unsigned long long*)p;
    p += (size_t)NB * sizeof(unsigned long long);                         // zeroed
    float* bn    = (float*)p; p += 256 * sizeof(float);                   // zeroed
    int*   off   = (int*)p;   p += ((size_t)N + 4) * sizeof(int);
    int*   srcs  = (int*)p;   p += (size_t)E * sizeof(int);

    size_t zbytes = (size_t)N * sizeof(int) + (size_t)NB * sizeof(unsigned long long)
                  + 256 * sizeof(float);

    dim3 blk(256);
    hipMemsetAsync(cnt, 0, zbytes, stream);
    k_count<<<dim3((E + 1023) / 1024), blk, 0, stream>>>(col, cnt, E);
    k_csr<<<dim3(NB), blk, 0, stream>>>(cnt, flags, off, dinv, N, NB);
    k_gemm<<<dim3((N + 127) / 128), blk, 0, stream>>>(x, W, dinv, (unsigned short*)xu, N);
    k_place<<<dim3((E + 511) / 512), blk, 0, stream>>>(row, col, off, cnt, srcs, E);
    k_gather<<<dim3(2048), blk, 0, stream>>>(xu, dinv, off, srcs, b, out, bn, N);
    int total4 = N * (HIDDEN / 4);
    k_apply<<<dim3((total4 + 255) / 256), blk, 0, stream>>>(out, bn, gamma, beta, total4,
                                                            1.0f / (float)N);
}